// Round 12
// baseline (70.853 us; speedup 1.0000x reference)
//
#include <hip/hip_runtime.h>

#define NPTS 8192
#define NB 2
#define NSPLIT 8                 // B-splits per (dir,batch)
#define FPS 32                   // fragments (32-pt tiles) per split
#define MROWS 256                // m-rows per block (4 waves x 2 mtiles x 32)
#define FMAX 3.4028235e38f

typedef __attribute__((ext_vector_type(8)))  short short8;
typedef __attribute__((ext_vector_type(16))) float f32x16;

__device__ __forceinline__ unsigned short bf16_rne(float f) {
    unsigned u = __float_as_uint(f);
    unsigned r = u + 0x7FFFu + ((u >> 16) & 1u);
    return (unsigned short)(r >> 16);
}
__device__ __forceinline__ float bf16_tof(unsigned short h) {
    return __uint_as_float(((unsigned)h) << 16);
}

// Grid (32 msuper, 4 db, 8 split) = 1024 blocks, 4 waves -> 4 blocks/CU,
// 4 waves/SIMD. Block: 256 m-rows x one 1024-point B-split.
// Convert -> LDS fragment tiles (lane-order: half h of record c at
// tile*1024 + h*512 + c*16 => sweep ds_read_b128 at lane*16, conflict-free).
// Sweep: 1 ds_read : 2 MFMA (2 m-tiles/wave) : 32 min3.
// Record K=16 slots: k0..2=yh(-2y) k3..5=yh k6..8=yl k9,10=1.0 k11=b2h
// k12=b2l k13..15=0 (verified in-situ R7-R11: absmax 0.0156 vs 0.047 thr).
__global__ __launch_bounds__(256, 4) void _chamfer_main(const float* __restrict__ x,
                                                        const float* __restrict__ y,
                                                        float* __restrict__ part) {
    const int msuper = blockIdx.x;      // 0..31
    const int db     = blockIdx.y;      // dir*NB+batch, 0..3
    const int split  = blockIdx.z;      // 0..7
    const int dir    = db >> 1;
    const int batch  = db & 1;

    const float* A = dir ? y : x;
    const float* B = dir ? x : y;

    // Union: staging fragments (32 KB) then row-reduce regions
    // 8 regions (4 waves x 2 mt) x 32 rows x stride-33 = 8448 floats = 33 KB.
    __shared__ __align__(16) float red[8 * 32 * 33];
    unsigned char* frag = (unsigned char*)red;

    const int t    = (int)threadIdx.x;
    const int lane = t & 63;
    const int wv   = t >> 6;
    const int col  = lane & 31;
    const int kg   = lane >> 5;

    // ---- convert split's 1024 B-points into LDS fragment tiles ----
    {
        // thread t owns 4 consecutive points = 48 B = 3 aligned float4
        const float4* bsrc = (const float4*)(B + ((size_t)batch * NPTS
                                                  + (size_t)split * 1024) * 3) + t * 3;
        const float4 q0 = bsrc[0], q1 = bsrc[1], q2 = bsrc[2];
        const float px[4] = {q0.x, q0.w, q1.z, q2.y};
        const float py[4] = {q0.y, q1.x, q1.w, q2.z};
        const float pz[4] = {q0.z, q1.y, q2.x, q2.w};
        #pragma unroll
        for (int i = 0; i < 4; ++i) {
            const int p = t * 4 + i;                     // 0..1023
            const float vx = px[i], vy = py[i], vz = pz[i];
            const float nx = -2.f*vx, ny = -2.f*vy, nz = -2.f*vz;
            const unsigned short h0 = bf16_rne(nx), h1 = bf16_rne(ny), h2 = bf16_rne(nz);
            const unsigned short l0 = bf16_rne(nx - bf16_tof(h0));
            const unsigned short l1 = bf16_rne(ny - bf16_tof(h1));
            const unsigned short l2 = bf16_rne(nz - bf16_tof(h2));
            const float b2 = vx*vx + vy*vy + vz*vz;
            const unsigned short bh = bf16_rne(b2);
            const unsigned short bl = bf16_rne(b2 - bf16_tof(bh));
            uint4 w0, w1;
            w0.x = (unsigned)h0 | ((unsigned)h1 << 16);   // k0,k1
            w0.y = (unsigned)h2 | ((unsigned)h0 << 16);   // k2,k3
            w0.z = (unsigned)h1 | ((unsigned)h2 << 16);   // k4,k5
            w0.w = (unsigned)l0 | ((unsigned)l1 << 16);   // k6,k7
            w1.x = (unsigned)l2 | (0x3F80u << 16);        // k8,k9
            w1.y = 0x3F80u | ((unsigned)bh << 16);        // k10,k11
            w1.z = (unsigned)bl;                          // k12,k13
            w1.w = 0u;                                    // k14,k15
            unsigned char* tile = frag + (size_t)(p >> 5) * 1024;
            *(uint4*)(tile + (size_t)(p & 31) * 16)       = w0;  // half 0
            *(uint4*)(tile + 512 + (size_t)(p & 31) * 16) = w1;  // half 1
        }
    }

    // ---- A-fragments: 2 m-tiles per wave ----
    short8 af[2];
    #pragma unroll
    for (int mt = 0; mt < 2; ++mt) {
        const int mrow = msuper * MROWS + wv * 64 + mt * 32 + col;
        const float* ap = A + ((size_t)batch * NPTS + mrow) * 3;
        const float vx = ap[0], vy = ap[1], vz = ap[2];
        const unsigned short h0 = bf16_rne(vx), h1 = bf16_rne(vy), h2 = bf16_rne(vz);
        const unsigned short l0 = bf16_rne(vx - bf16_tof(h0));
        const unsigned short l1 = bf16_rne(vy - bf16_tof(h1));
        const unsigned short l2 = bf16_rne(vz - bf16_tof(h2));
        const float a2 = vx*vx + vy*vy + vz*vz;
        const unsigned short ah = bf16_rne(a2);
        const unsigned short al = bf16_rne(a2 - bf16_tof(ah));
        const unsigned short ONE = 0x3F80u;
        if (kg == 0) {
            af[mt][0]=(short)h0; af[mt][1]=(short)h1; af[mt][2]=(short)h2;
            af[mt][3]=(short)l0; af[mt][4]=(short)l1; af[mt][5]=(short)l2;
            af[mt][6]=(short)h0; af[mt][7]=(short)h1;
        } else {
            af[mt][0]=(short)h2; af[mt][1]=(short)ah; af[mt][2]=(short)al;
            af[mt][3]=(short)ONE; af[mt][4]=(short)ONE;
            af[mt][5]=0; af[mt][6]=0; af[mt][7]=0;
        }
    }

    f32x16 z, rm[2];
    #pragma unroll
    for (int q = 0; q < 16; ++q) { z[q] = 0.f; rm[0][q] = FMAX; rm[1][q] = FMAX; }

    __syncthreads();

    // ---- sweep 32 fragments ----
    const unsigned char* fb = frag + (size_t)lane * 16;
    #pragma unroll 2
    for (int ff = 0; ff < FPS; ff += 2) {
        const short8 b0 = *(const short8*)(fb + (size_t)ff * 1024);
        const short8 b1 = *(const short8*)(fb + (size_t)ff * 1024 + 1024);
        #pragma unroll
        for (int mt = 0; mt < 2; ++mt) {
            const f32x16 d0 = __builtin_amdgcn_mfma_f32_32x32x16_bf16(af[mt], b0, z, 0, 0, 0);
            const f32x16 d1 = __builtin_amdgcn_mfma_f32_32x32x16_bf16(af[mt], b1, z, 0, 0, 0);
            #pragma unroll
            for (int q = 0; q < 16; ++q)
                rm[mt][q] = fminf(fminf(rm[mt][q], d0[q]), d1[q]);   // v_min3_f32
        }
    }

    // ---- row reduce: both mt rounds in disjoint regions, ONE sync pair ----
    __syncthreads();     // sweep done: safe to overwrite staging LDS
    #pragma unroll
    for (int mt = 0; mt < 2; ++mt) {
        #pragma unroll
        for (int q = 0; q < 16; ++q) {
            const int r = (q & 3) + 8 * (q >> 2) + 4 * kg;   // C-layout row
            red[(wv * 2 + mt) * 1056 + r * 33 + col] = rm[mt][q];
        }
    }
    __syncthreads();
    if (lane < 32) {
        // two independent 31-min chains (ILP 2); stride-33 -> conflict-free
        const float* p0 = red + (wv * 2 + 0) * 1056 + lane * 33;
        const float* p1 = red + (wv * 2 + 1) * 1056 + lane * 33;
        float m0 = p0[0], m1 = p1[0];
        #pragma unroll
        for (int c = 1; c < 32; ++c) { m0 = fminf(m0, p0[c]); m1 = fminf(m1, p1[c]); }
        const int row0 = msuper * MROWS + wv * 64 + lane;
        // part layout [db][row][split]: reduce reads 2 coalesced float4
        part[((size_t)db * NPTS + row0)      * NSPLIT + split] = m0;
        part[((size_t)db * NPTS + row0 + 32) * NSPLIT + split] = m1;
    }
}

// Final: min over 8 consecutive split partials + clamp.
// out = dl(2x8192) then dr(2x8192); out index w == db*8192+i matches part rows.
__global__ __launch_bounds__(256) void _chamfer_reduce(const float* __restrict__ part,
                                                       float* __restrict__ out) {
    const int w = blockIdx.x * 256 + (int)threadIdx.x;    // 0..32767
    const float4* p = (const float4*)(part + (size_t)w * NSPLIT);
    const float4 a = p[0], b = p[1];
    float m = fminf(fminf(fminf(a.x, a.y), fminf(a.z, a.w)),
                    fminf(fminf(b.x, b.y), fminf(b.z, b.w)));
    out[w] = fmaxf(m, 0.f);
}

extern "C" void kernel_launch(void* const* d_in, const int* in_sizes, int n_in,
                              void* d_out, int out_size, void* d_ws, size_t ws_size,
                              hipStream_t stream) {
    const float* x = (const float*)d_in[0];
    const float* y = (const float*)d_in[1];
    float* part = (float*)d_ws;          // 4 db x 8192 rows x 8 splits = 1 MiB
    float* out  = (float*)d_out;

    _chamfer_main<<<dim3(32, 4, NSPLIT), dim3(256), 0, stream>>>(x, y, part);
    _chamfer_reduce<<<dim3(out_size / 256), dim3(256), 0, stream>>>(part, out);
}

// Round 15
// 65.433 us; speedup vs baseline: 1.0828x; 1.0828x over previous
//
#include <hip/hip_runtime.h>

#define NPTS 8192
#define NB 2
#define NSPLIT 8                 // B-splits per (dir,batch)
#define FPS 32                   // fragments (32-pt tiles) per split
#define MROWS 256                // m-rows per block (4 waves x 2 mtiles x 32)
#define FMAX 3.4028235e38f

typedef __attribute__((ext_vector_type(8)))  short short8;
typedef __attribute__((ext_vector_type(16))) float f32x16;

__device__ __forceinline__ unsigned short bf16_rne(float f) {
    unsigned u = __float_as_uint(f);
    unsigned r = u + 0x7FFFu + ((u >> 16) & 1u);
    return (unsigned short)(r >> 16);
}
__device__ __forceinline__ float bf16_tof(unsigned short h) {
    return __uint_as_float(((unsigned)h) << 16);
}

// R11 configuration (best measured: 65.9 us total).
// Grid (32 msuper, 4 db, 8 split) = 1024 blocks, 4 waves -> 4 blocks/CU,
// 4 waves/SIMD. Block: 256 m-rows x one 1024-point B-split.
// Convert -> LDS fragment tiles (lane-order: half h of record c at
// tile*1024 + h*512 + c*16 => sweep ds_read_b128 at lane*16, conflict-free).
// Sweep: 1 ds_read : 2 MFMA (2 m-tiles/wave) : 32 min3.
// Record K=16 slots: k0..2=yh(-2y) k3..5=yh k6..8=yl k9,10=1.0 k11=b2h
// k12=b2l k13..15=0 (verified in-situ R7-R12: absmax 0.0156 vs 0.047 thr).
__global__ __launch_bounds__(256, 4) void _chamfer_main(const float* __restrict__ x,
                                                        const float* __restrict__ y,
                                                        float* __restrict__ part) {
    const int msuper = blockIdx.x;      // 0..31
    const int db     = blockIdx.y;      // dir*NB+batch, 0..3
    const int split  = blockIdx.z;      // 0..7
    const int dir    = db >> 1;
    const int batch  = db & 1;

    const float* A = dir ? y : x;
    const float* B = dir ? x : y;

    __shared__ unsigned char lds[FPS * 1024];   // 32 KB fragments; reused for red

    const int t    = (int)threadIdx.x;
    const int lane = t & 63;
    const int wv   = t >> 6;
    const int col  = lane & 31;
    const int kg   = lane >> 5;

    // ---- convert split's 1024 B-points into LDS fragment tiles ----
    {
        const float* bsrc = B + ((size_t)batch * NPTS + (size_t)split * 1024) * 3;
        #pragma unroll
        for (int rr = 0; rr < 4; ++rr) {
            const int p = rr * 256 + t;                  // 0..1023
            const float* sp = bsrc + (size_t)p * 3;
            const float vx = sp[0], vy = sp[1], vz = sp[2];
            const float nx = -2.f*vx, ny = -2.f*vy, nz = -2.f*vz;
            const unsigned short h0 = bf16_rne(nx), h1 = bf16_rne(ny), h2 = bf16_rne(nz);
            const unsigned short l0 = bf16_rne(nx - bf16_tof(h0));
            const unsigned short l1 = bf16_rne(ny - bf16_tof(h1));
            const unsigned short l2 = bf16_rne(nz - bf16_tof(h2));
            const float b2 = vx*vx + vy*vy + vz*vz;
            const unsigned short bh = bf16_rne(b2);
            const unsigned short bl = bf16_rne(b2 - bf16_tof(bh));
            uint4 w0, w1;
            w0.x = (unsigned)h0 | ((unsigned)h1 << 16);   // k0,k1
            w0.y = (unsigned)h2 | ((unsigned)h0 << 16);   // k2,k3
            w0.z = (unsigned)h1 | ((unsigned)h2 << 16);   // k4,k5
            w0.w = (unsigned)l0 | ((unsigned)l1 << 16);   // k6,k7
            w1.x = (unsigned)l2 | (0x3F80u << 16);        // k8,k9
            w1.y = 0x3F80u | ((unsigned)bh << 16);        // k10,k11
            w1.z = (unsigned)bl;                          // k12,k13
            w1.w = 0u;                                    // k14,k15
            unsigned char* tile = lds + (size_t)(p >> 5) * 1024;
            *(uint4*)(tile + (size_t)(p & 31) * 16)       = w0;  // half 0
            *(uint4*)(tile + 512 + (size_t)(p & 31) * 16) = w1;  // half 1
        }
    }

    // ---- A-fragments: 2 m-tiles per wave (bf16x3 split + |a|^2 hi/lo) ----
    short8 af[2];
    #pragma unroll
    for (int mt = 0; mt < 2; ++mt) {
        const int mrow = msuper * MROWS + wv * 64 + mt * 32 + col;
        const float* ap = A + ((size_t)batch * NPTS + mrow) * 3;
        const float vx = ap[0], vy = ap[1], vz = ap[2];
        const unsigned short h0 = bf16_rne(vx), h1 = bf16_rne(vy), h2 = bf16_rne(vz);
        const unsigned short l0 = bf16_rne(vx - bf16_tof(h0));
        const unsigned short l1 = bf16_rne(vy - bf16_tof(h1));
        const unsigned short l2 = bf16_rne(vz - bf16_tof(h2));
        const float a2 = vx*vx + vy*vy + vz*vz;
        const unsigned short ah = bf16_rne(a2);
        const unsigned short al = bf16_rne(a2 - bf16_tof(ah));
        const unsigned short ONE = 0x3F80u;
        if (kg == 0) {
            af[mt][0]=(short)h0; af[mt][1]=(short)h1; af[mt][2]=(short)h2;
            af[mt][3]=(short)l0; af[mt][4]=(short)l1; af[mt][5]=(short)l2;
            af[mt][6]=(short)h0; af[mt][7]=(short)h1;
        } else {
            af[mt][0]=(short)h2; af[mt][1]=(short)ah; af[mt][2]=(short)al;
            af[mt][3]=(short)ONE; af[mt][4]=(short)ONE;
            af[mt][5]=0; af[mt][6]=0; af[mt][7]=0;
        }
    }

    f32x16 z, rm[2];
    #pragma unroll
    for (int q = 0; q < 16; ++q) { z[q] = 0.f; rm[0][q] = FMAX; rm[1][q] = FMAX; }

    __syncthreads();

    // ---- sweep 32 fragments; 1 ds_read : 2 MFMA : 32 min3 ----
    const unsigned char* fb = lds + (size_t)lane * 16;
    #pragma unroll 4
    for (int ff = 0; ff < FPS; ff += 2) {
        const short8 b0 = *(const short8*)(fb + (size_t)ff * 1024);
        const short8 b1 = *(const short8*)(fb + (size_t)ff * 1024 + 1024);
        #pragma unroll
        for (int mt = 0; mt < 2; ++mt) {
            const f32x16 d0 = __builtin_amdgcn_mfma_f32_32x32x16_bf16(af[mt], b0, z, 0, 0, 0);
            const f32x16 d1 = __builtin_amdgcn_mfma_f32_32x32x16_bf16(af[mt], b1, z, 0, 0, 0);
            #pragma unroll
            for (int q = 0; q < 16; ++q)
                rm[mt][q] = fminf(fminf(rm[mt][q], d0[q]), d1[q]);   // v_min3_f32
        }
    }

    // ---- per-wave row reduce, two rounds (LDS region reused) ----
    float* red = (float*)lds;            // 4 x 32 x 33 floats = 16.9 KB
    float* po  = part + ((size_t)(db * NSPLIT + split) * NPTS) + msuper * MROWS;
    #pragma unroll
    for (int mt = 0; mt < 2; ++mt) {
        __syncthreads();
        #pragma unroll
        for (int q = 0; q < 16; ++q) {
            const int r = (q & 3) + 8 * (q >> 2) + 4 * kg;   // C-layout row
            red[wv * 1056 + r * 33 + col] = rm[mt][q];
        }
        __syncthreads();
        if (lane < 32) {
            const float* pr = red + wv * 1056 + lane * 33;
            float m = pr[0];
            #pragma unroll
            for (int c = 1; c < 32; ++c) m = fminf(m, pr[c]);
            po[wv * 64 + mt * 32 + lane] = m;
        }
    }
}

// Final: min over the 8 split partials + clamp. out = dl(2x8192) then dr(2x8192).
__global__ __launch_bounds__(256) void _chamfer_reduce(const float* __restrict__ part,
                                                       float* __restrict__ out) {
    const int w = blockIdx.x * 256 + (int)threadIdx.x;    // 0..32767
    const int db = w >> 13, i = w & (NPTS - 1);
    const float* p = part + ((size_t)db * NSPLIT) * NPTS + i;
    float m = p[0];
    #pragma unroll
    for (int s = 1; s < NSPLIT; ++s) m = fminf(m, p[(size_t)s * NPTS]);
    out[w] = fmaxf(m, 0.f);
}

extern "C" void kernel_launch(void* const* d_in, const int* in_sizes, int n_in,
                              void* d_out, int out_size, void* d_ws, size_t ws_size,
                              hipStream_t stream) {
    const float* x = (const float*)d_in[0];
    const float* y = (const float*)d_in[1];
    float* part = (float*)d_ws;          // 4 db x 8 splits x 8192 = 1 MiB
    float* out  = (float*)d_out;

    _chamfer_main<<<dim3(32, 4, NSPLIT), dim3(256), 0, stream>>>(x, y, part);
    _chamfer_reduce<<<dim3(out_size / 256), dim3(256), 0, stream>>>(part, out);
}